// Round 1
// baseline (440.941 us; speedup 1.0000x reference)
//
#include <hip/hip_runtime.h>
#include <hip/hip_bf16.h>

#define EMBED 768
#define FFNDIM 3072
#define HEADS 12
#define HDIM  64
#define BB    4
#define TT    2048
#define MTOK  (BB*TT)   // 8192 tokens

typedef __hip_bfloat16 bf16;
typedef __attribute__((ext_vector_type(8))) short short8;
typedef __attribute__((ext_vector_type(4))) float f32x4;
typedef __attribute__((ext_vector_type(4))) unsigned short ushort4v;

__device__ __forceinline__ f32x4 mfma16(short8 a, short8 b, f32x4 c) {
  return __builtin_amdgcn_mfma_f32_16x16x32_bf16(a, b, c, 0, 0, 0);
}

__device__ __forceinline__ unsigned short f2bf(float f) {
  union { float f; unsigned int u; } v; v.f = f;
  unsigned int u = v.u;
  return (unsigned short)((u + 0x7fffu + ((u >> 16) & 1u)) >> 16);
}

// async global->LDS, 16B per lane; lds dest must be wave-uniform (HW: base + lane*16)
__device__ __forceinline__ void gl_lds16(const void* g, void* l) {
  __builtin_amdgcn_global_load_lds((const __attribute__((address_space(1))) void*)g,
                                   (__attribute__((address_space(3))) void*)l, 16, 0, 0);
}

// ---------------------------------------------------------------------------
// weight transpose + cast: W[K][N] fp32 -> Wt[N][K] bf16
// ---------------------------------------------------------------------------
struct TArgs {
  const float* src[6];
  bf16* dst[6];
  int K[6];
  int N[6];
};

__global__ __launch_bounds__(256) void transpose_k(TArgs ta) {
  const int mi = blockIdx.z;
  const int K = ta.K[mi], N = ta.N[mi];
  const int n0 = blockIdx.x * 32, k0 = blockIdx.y * 32;
  if (n0 >= N || k0 >= K) return;
  __shared__ float t[32][33];
  const float* __restrict__ W = ta.src[mi];
  bf16* __restrict__ Wt = ta.dst[mi];
  const int tx = threadIdx.x & 31, ty = threadIdx.x >> 5;
#pragma unroll
  for (int i = 0; i < 4; ++i) {
    int kk = ty + i * 8;
    t[tx][kk] = W[(size_t)(k0 + kk) * N + n0 + tx];
  }
  __syncthreads();
#pragma unroll
  for (int i = 0; i < 4; ++i) {
    int nn = ty + i * 8;
    Wt[(size_t)(n0 + nn) * K + k0 + tx] = __float2bfloat16(t[nn][tx]);
  }
}

// ---------------------------------------------------------------------------
// LayerNorm: one wave per row (768 = 64 lanes x 12 elems), fp32 in -> bf16 out
// ---------------------------------------------------------------------------
__global__ __launch_bounds__(256) void ln_k(const float* __restrict__ x,
                                            const float* __restrict__ g,
                                            const float* __restrict__ b,
                                            bf16* __restrict__ out) {
  const int row = blockIdx.x * 4 + (threadIdx.x >> 6);
  const int lane = threadIdx.x & 63;
  const float* xr = x + (size_t)row * EMBED;
  float4 v[3];
  float s = 0.f;
#pragma unroll
  for (int i = 0; i < 3; ++i) {
    v[i] = *(const float4*)&xr[i * 256 + lane * 4];
    s += v[i].x + v[i].y + v[i].z + v[i].w;
  }
#pragma unroll
  for (int m = 1; m < 64; m <<= 1) s += __shfl_xor(s, m);
  const float mean = s * (1.f / 768.f);
  float ss = 0.f;
#pragma unroll
  for (int i = 0; i < 3; ++i) {
    float dx = v[i].x - mean, dy = v[i].y - mean, dz = v[i].z - mean, dw = v[i].w - mean;
    ss += dx * dx + dy * dy + dz * dz + dw * dw;
  }
#pragma unroll
  for (int m = 1; m < 64; m <<= 1) ss += __shfl_xor(ss, m);
  const float rstd = rsqrtf(ss * (1.f / 768.f) + 1e-5f);
#pragma unroll
  for (int i = 0; i < 3; ++i) {
    float4 g4 = *(const float4*)&g[i * 256 + lane * 4];
    float4 b4 = *(const float4*)&b[i * 256 + lane * 4];
    ushort4v o4;
    o4[0] = f2bf((v[i].x - mean) * rstd * g4.x + b4.x);
    o4[1] = f2bf((v[i].y - mean) * rstd * g4.y + b4.y);
    o4[2] = f2bf((v[i].z - mean) * rstd * g4.z + b4.z);
    o4[3] = f2bf((v[i].w - mean) * rstd * g4.w + b4.w);
    *(ushort4v*)&out[(size_t)row * EMBED + i * 256 + lane * 4] = o4;
  }
}

// ---------------------------------------------------------------------------
// GEMM: C[M][N] = A[M][K] @ Bt[N][K]^T, bf16 inputs, fp32 accum.
// 128x128 tile, BK=32, 4 waves (2x2 of 64x64), 16x16x32 MFMA (m97 structure).
// EPI 0: fused QKV (q,k bf16 row-major; v written transposed [b,h,d,t])
// EPI 1: outf = resid + C + bias  (fp32)
// EPI 2: outb = gelu(C + bias)    (bf16)
// ---------------------------------------------------------------------------
template <int EPI>
__global__ __launch_bounds__(256) void gemm_bt_k(
    const bf16* __restrict__ A, const bf16* __restrict__ Bt,
    const float* __restrict__ bias, const float* __restrict__ bias2,
    const float* __restrict__ bias3, const float* __restrict__ resid,
    float* __restrict__ outf, bf16* __restrict__ outb,
    bf16* __restrict__ outk, bf16* __restrict__ outvt,
    int N, int K) {
  const int tid = threadIdx.x;
  const int lane = tid & 63;
  const int w = tid >> 6;
  const int wr = w >> 1, wc = w & 1;
  const int l16 = lane & 15, g = lane >> 4;
  const int m0 = blockIdx.y * 128, n0 = blockIdx.x * 128;

  __shared__ bf16 Al[128 * 32];
  __shared__ bf16 Bl[128 * 32];

  f32x4 acc[4][4];
#pragma unroll
  for (int i = 0; i < 4; ++i)
#pragma unroll
    for (int j = 0; j < 4; ++j) acc[i][j] = {0.f, 0.f, 0.f, 0.f};

  const int st_r = lane >> 2;        // 0..15 (row within 16-row chunk)
  const int st_c = (lane & 3) * 8;   // elem offset within 32-elem row
  const size_t a_base = (size_t)(m0 + w * 32) * K;
  const size_t b_base = (size_t)(n0 + w * 32) * K;

  for (int kt = 0; kt < K; kt += 32) {
    __syncthreads();
#pragma unroll
    for (int p = 0; p < 2; ++p) {
      gl_lds16(A + a_base + (size_t)(p * 16 + st_r) * K + kt + st_c,
               &Al[(w * 32 + p * 16) * 32]);
      gl_lds16(Bt + b_base + (size_t)(p * 16 + st_r) * K + kt + st_c,
               &Bl[(w * 32 + p * 16) * 32]);
    }
    __syncthreads();

    short8 af[4], bfr[4];
#pragma unroll
    for (int i = 0; i < 4; ++i)
      af[i] = *(const short8*)&Al[(wr * 64 + i * 16 + l16) * 32 + g * 8];
#pragma unroll
    for (int j = 0; j < 4; ++j)
      bfr[j] = *(const short8*)&Bl[(wc * 64 + j * 16 + l16) * 32 + g * 8];
#pragma unroll
    for (int i = 0; i < 4; ++i)
#pragma unroll
      for (int j = 0; j < 4; ++j) acc[i][j] = mfma16(af[i], bfr[j], acc[i][j]);
  }

  // epilogue: C element (m = crow + i*16 + rr, n = ccol + j*16)
  const int crow = m0 + wr * 64 + g * 4;
  const int ccol = n0 + wc * 64 + l16;

  if constexpr (EPI == 0) {
    const int region = n0 / EMBED;  // tile never straddles a 768 boundary
    const float* bp = (region == 0) ? bias : (region == 1) ? bias2 : bias3;
    if (region < 2) {
      bf16* __restrict__ dst = (region == 0) ? outb : outk;
#pragma unroll
      for (int j = 0; j < 4; ++j) {
        const int cn = ccol - region * EMBED + j * 16;
        const float bvv = bp[cn];
#pragma unroll
        for (int i = 0; i < 4; ++i)
#pragma unroll
          for (int rr = 0; rr < 4; ++rr) {
            const int m = crow + i * 16 + rr;
            dst[(size_t)m * EMBED + cn] = __float2bfloat16(acc[i][j][rr] + bvv);
          }
      }
    } else {
#pragma unroll
      for (int j = 0; j < 4; ++j) {
        const int cn = ccol - 2 * EMBED + j * 16;
        const float bvv = bp[cn];
        const int hh = cn >> 6, dd = cn & 63;
#pragma unroll
        for (int i = 0; i < 4; ++i) {
          const int m = crow + i * 16;     // rr gives 4 consecutive t
          const int bb2 = m >> 11, t = m & 2047;
          ushort4v pk;
#pragma unroll
          for (int rr = 0; rr < 4; ++rr) pk[rr] = f2bf(acc[i][j][rr] + bvv);
          *(ushort4v*)&outvt[((size_t)((bb2 * HEADS + hh) * HDIM + dd)) * TT + t] = pk;
        }
      }
    }
  } else if constexpr (EPI == 1) {
#pragma unroll
    for (int j = 0; j < 4; ++j) {
      const int cn = ccol + j * 16;
      const float bvv = bias[cn];
#pragma unroll
      for (int i = 0; i < 4; ++i)
#pragma unroll
        for (int rr = 0; rr < 4; ++rr) {
          const int m = crow + i * 16 + rr;
          const size_t idx = (size_t)m * N + cn;
          outf[idx] = resid[idx] + acc[i][j][rr] + bvv;
        }
    }
  } else {  // EPI == 2: gelu -> bf16
#pragma unroll
    for (int j = 0; j < 4; ++j) {
      const int cn = ccol + j * 16;
      const float bvv = bias[cn];
#pragma unroll
      for (int i = 0; i < 4; ++i)
#pragma unroll
        for (int rr = 0; rr < 4; ++rr) {
          const int m = crow + i * 16 + rr;
          const float v = acc[i][j][rr] + bvv;
          const float ge = 0.5f * v * (1.f + erff(v * 0.70710678118f));
          outb[(size_t)m * N + cn] = __float2bfloat16(ge);
        }
    }
  }
}

// ---------------------------------------------------------------------------
// Flash attention (non-causal). Block = (qt, h, b); 4 waves; QBLK=64, KBLK=64.
// q,k: [b*T+t][h*64+d] bf16 ; vt: [((b*H+h)*64+d)*T + t] bf16 (transposed).
// Per wave: 16 q-rows. Online softmax in fp32.
// ---------------------------------------------------------------------------
__global__ __launch_bounds__(256) void flash_k(const bf16* __restrict__ q,
                                               const bf16* __restrict__ k,
                                               const bf16* __restrict__ vt,
                                               bf16* __restrict__ o) {
  const int qt = blockIdx.x;  // 0..31
  const int h = blockIdx.y;   // 0..11
  const int b = blockIdx.z;   // 0..3
  const int tid = threadIdx.x, lane = tid & 63, w = tid >> 6;
  const int l16 = lane & 15, g = lane >> 4;

  __shared__ bf16 Kl[64][72];      // rows = kk, cols = d   (pad 144B = 9x16B)
  __shared__ bf16 Vl[64][72];      // rows = d,  cols = kk
  __shared__ bf16 Pl[4][16][72];   // per-wave P tile [q-local][kk]

  short8 qf[2];
  {
    const size_t qbase =
        (size_t)(b * TT + qt * 64 + w * 16 + l16) * EMBED + h * HDIM + g * 8;
    qf[0] = *(const short8*)&q[qbase];
    qf[1] = *(const short8*)&q[qbase + 32];
  }

  f32x4 oacc[4];
#pragma unroll
  for (int jd = 0; jd < 4; ++jd) oacc[jd] = {0.f, 0.f, 0.f, 0.f};
  float mrun[4], lrun[4];
#pragma unroll
  for (int r = 0; r < 4; ++r) { mrun[r] = -3.0e38f; lrun[r] = 0.f; }

  const bf16* kg = k + (size_t)(b * TT) * EMBED + h * HDIM;
  const bf16* vg = vt + (size_t)((b * HEADS + h) * HDIM) * TT;

  const int st_r = tid >> 3;        // 0..31
  const int st_c = (tid & 7) * 8;   // 0..56

  for (int kt = 0; kt < TT / 64; ++kt) {
    __syncthreads();
#pragma unroll
    for (int p = 0; p < 2; ++p) {
      const int row = p * 32 + st_r;
      *(short8*)&Kl[row][st_c] =
          *(const short8*)&kg[(size_t)(kt * 64 + row) * EMBED + st_c];
      *(short8*)&Vl[row][st_c] =
          *(const short8*)&vg[(size_t)row * TT + kt * 64 + st_c];
    }
    __syncthreads();

    // S = Q K^T  (rows = q-local, cols = kk 0..63), then *1/sqrt(64)
    f32x4 s[4];
#pragma unroll
    for (int j = 0; j < 4; ++j) {
      short8 kf0 = *(const short8*)&Kl[j * 16 + l16][g * 8];
      short8 kf1 = *(const short8*)&Kl[j * 16 + l16][32 + g * 8];
      f32x4 t = {0.f, 0.f, 0.f, 0.f};
      t = mfma16(qf[0], kf0, t);
      t = mfma16(qf[1], kf1, t);
      s[j] = t * 0.125f;
    }

    float alpha[4];
#pragma unroll
    for (int r = 0; r < 4; ++r) {
      float mx = fmaxf(fmaxf(s[0][r], s[1][r]), fmaxf(s[2][r], s[3][r]));
      mx = fmaxf(mx, __shfl_xor(mx, 1));
      mx = fmaxf(mx, __shfl_xor(mx, 2));
      mx = fmaxf(mx, __shfl_xor(mx, 4));
      mx = fmaxf(mx, __shfl_xor(mx, 8));
      const float mn = fmaxf(mrun[r], mx);
      alpha[r] = __expf(mrun[r] - mn);
      float ps = 0.f;
#pragma unroll
      for (int j = 0; j < 4; ++j) {
        const float pv = __expf(s[j][r] - mn);
        s[j][r] = pv;
        ps += pv;
      }
      ps += __shfl_xor(ps, 1);
      ps += __shfl_xor(ps, 2);
      ps += __shfl_xor(ps, 4);
      ps += __shfl_xor(ps, 8);
      lrun[r] = lrun[r] * alpha[r] + ps;
      mrun[r] = mn;
    }

#pragma unroll
    for (int jd = 0; jd < 4; ++jd)
#pragma unroll
      for (int r = 0; r < 4; ++r) oacc[jd][r] *= alpha[r];

    // P (C-layout) -> LDS -> A-layout
#pragma unroll
    for (int j = 0; j < 4; ++j)
#pragma unroll
      for (int r = 0; r < 4; ++r)
        Pl[w][g * 4 + r][j * 16 + l16] = __float2bfloat16(s[j][r]);

    short8 pa0 = *(const short8*)&Pl[w][l16][g * 8];
    short8 pa1 = *(const short8*)&Pl[w][l16][32 + g * 8];
#pragma unroll
    for (int jd = 0; jd < 4; ++jd) {
      short8 vf0 = *(const short8*)&Vl[jd * 16 + l16][g * 8];
      short8 vf1 = *(const short8*)&Vl[jd * 16 + l16][32 + g * 8];
      oacc[jd] = mfma16(pa0, vf0, oacc[jd]);
      oacc[jd] = mfma16(pa1, vf1, oacc[jd]);
    }
  }

#pragma unroll
  for (int jd = 0; jd < 4; ++jd)
#pragma unroll
    for (int r = 0; r < 4; ++r) {
      const float val = oacc[jd][r] / lrun[r];
      const int t = qt * 64 + w * 16 + g * 4 + r;
      o[(size_t)(b * TT + t) * EMBED + h * HDIM + jd * 16 + l16] =
          __float2bfloat16(val);
    }
}

// ---------------------------------------------------------------------------
extern "C" void kernel_launch(void* const* d_in, const int* in_sizes, int n_in,
                              void* d_out, int out_size, void* d_ws,
                              size_t ws_size, hipStream_t stream) {
  const float* x = (const float*)d_in[0];
  const float* ln1g = (const float*)d_in[1];
  const float* ln1b = (const float*)d_in[2];
  const float* wq = (const float*)d_in[3];
  const float* bq = (const float*)d_in[4];
  const float* wk = (const float*)d_in[5];
  const float* bk = (const float*)d_in[6];
  const float* wv = (const float*)d_in[7];
  const float* bv = (const float*)d_in[8];
  const float* wo = (const float*)d_in[9];
  const float* bo = (const float*)d_in[10];
  const float* ln2g = (const float*)d_in[11];
  const float* ln2b = (const float*)d_in[12];
  const float* w1 = (const float*)d_in[13];
  const float* b1 = (const float*)d_in[14];
  const float* w2 = (const float*)d_in[15];
  const float* b2 = (const float*)d_in[16];
  float* out = (float*)d_out;

  char* ws = (char*)d_ws;
  size_t off = 0;
  auto alloc = [&](size_t bytes) {
    char* p = ws + off;
    off += (bytes + 255) & ~(size_t)255;
    return p;
  };
  bf16* wqkv_t = (bf16*)alloc((size_t)2304 * 768 * 2);
  bf16* wo_t = (bf16*)alloc((size_t)768 * 768 * 2);
  bf16* w1_t = (bf16*)alloc((size_t)3072 * 768 * 2);
  bf16* w2_t = (bf16*)alloc((size_t)768 * 3072 * 2);
  bf16* h = (bf16*)alloc((size_t)MTOK * EMBED * 2);
  // qb/kb/vtb/ob are dead once attention-out GEMM runs; h1 overlays them (4x12.58MB = 50.3MB)
  char* qkvo = alloc((size_t)MTOK * EMBED * 2 * 4);
  bf16* qb = (bf16*)qkvo;
  bf16* kb = qb + (size_t)MTOK * EMBED;
  bf16* vtb = kb + (size_t)MTOK * EMBED;
  bf16* ob = vtb + (size_t)MTOK * EMBED;
  bf16* h1 = (bf16*)qkvo;  // [MTOK][3072] bf16, overlays q/k/vt/o
  float* x1 = (float*)alloc((size_t)MTOK * EMBED * 4);
  (void)ws_size;  // ~78 MB used

  TArgs ta;
  ta.src[0] = wq; ta.dst[0] = wqkv_t;                  ta.K[0] = 768;  ta.N[0] = 768;
  ta.src[1] = wk; ta.dst[1] = wqkv_t + 768 * 768;      ta.K[1] = 768;  ta.N[1] = 768;
  ta.src[2] = wv; ta.dst[2] = wqkv_t + 2 * 768 * 768;  ta.K[2] = 768;  ta.N[2] = 768;
  ta.src[3] = wo; ta.dst[3] = wo_t;                    ta.K[3] = 768;  ta.N[3] = 768;
  ta.src[4] = w1; ta.dst[4] = w1_t;                    ta.K[4] = 768;  ta.N[4] = 3072;
  ta.src[5] = w2; ta.dst[5] = w2_t;                    ta.K[5] = 3072; ta.N[5] = 768;

  transpose_k<<<dim3(96, 96, 6), dim3(256), 0, stream>>>(ta);
  ln_k<<<dim3(MTOK / 4), dim3(256), 0, stream>>>(x, ln1g, ln1b, h);
  gemm_bt_k<0><<<dim3(2304 / 128, MTOK / 128), dim3(256), 0, stream>>>(
      h, wqkv_t, bq, bk, bv, nullptr, nullptr, qb, kb, vtb, 2304, 768);
  flash_k<<<dim3(32, HEADS, BB), dim3(256), 0, stream>>>(qb, kb, vtb, ob);
  gemm_bt_k<1><<<dim3(768 / 128, MTOK / 128), dim3(256), 0, stream>>>(
      ob, wo_t, bo, nullptr, nullptr, x, x1, nullptr, nullptr, nullptr, 768, 768);
  ln_k<<<dim3(MTOK / 4), dim3(256), 0, stream>>>(x1, ln2g, ln2b, h);
  gemm_bt_k<2><<<dim3(3072 / 128, MTOK / 128), dim3(256), 0, stream>>>(
      h, w1_t, b1, nullptr, nullptr, nullptr, nullptr, h1, nullptr, nullptr, 3072, 768);
  gemm_bt_k<1><<<dim3(768 / 128, MTOK / 128), dim3(256), 0, stream>>>(
      h1, w2_t, b2, nullptr, nullptr, x1, out, nullptr, nullptr, nullptr, 768, 3072);
}